// Round 4
// baseline (254.372 us; speedup 1.0000x reference)
//
#include <hip/hip_runtime.h>

#define HW    3136
#define HDIM  56
#define CIN   256
#define CR    64
#define NG    16
#define CG    16
#define KK    49
#define BEPS  1e-5f
#define RB    4            // rows per band in k2
#define NBAND 14           // 56 / RB
#define PXB   (RB * HDIM)  // 224 pixels per band
#define WSTR  228          // w_lds row stride (224 px + 4 pad)

// k0: fold BN into conv1 weights, transpose to [c][o].
__global__ __launch_bounds__(256) void k0_fold(
    const float* __restrict__ W1, const float* __restrict__ b1,
    const float* __restrict__ gamma, const float* __restrict__ beta,
    const float* __restrict__ mean, const float* __restrict__ var,
    float* __restrict__ W1f, float* __restrict__ b1f)
{
    int idx = blockIdx.x * 256 + threadIdx.x;      // 0..16383
    int o = idx & 63, c = idx >> 6;
    float s = gamma[o] * rsqrtf(var[o] + BEPS);
    W1f[c * CR + o] = W1[o * CIN + c] * s;
    if (idx < CR) b1f[idx] = b1[idx] * s + beta[idx] - mean[idx] * s;
}

// k1: t[b][o][px] = relu(x . W1f + b1f), c-major output.
// Block 256 = 64 px-lanes x 4 K-quarters; 16 outputs/thread; LDS K-reduction.
// Grid: (49 px-tiles, 4 out-groups, 4 batch).
__global__ __launch_bounds__(256) void k1_conv(
    const float* __restrict__ x, const float* __restrict__ W1f,
    const float* __restrict__ b1f, float* __restrict__ t_out)
{
    __shared__ float part[4][64][16];   // 16 KB [kq][px][o_local]

    const int tid = threadIdx.x;
    const int pxl = tid & 63, kq = tid >> 6;
    const int og = blockIdx.y;          // outputs og*16 .. +15
    const int b  = blockIdx.z;
    const int px0 = blockIdx.x * 64;

    {
        const float* xb = x + (size_t)b * CIN * HW + px0 + pxl;
        const float* w1 = W1f + og * 16;     // + c*CR
        float acc[16];
#pragma unroll
        for (int o = 0; o < 16; o++) acc[o] = 0.f;
        const int c0 = kq * 64;
#pragma unroll 8
        for (int ci = 0; ci < 64; ci++) {
            float xv = xb[(size_t)(c0 + ci) * HW];
            const float* wr = w1 + (c0 + ci) * CR;   // wave-uniform -> s_load
#pragma unroll
            for (int o = 0; o < 16; o++) acc[o] += xv * wr[o];
        }
#pragma unroll
        for (int o4 = 0; o4 < 4; o4++)
            *(float4*)&part[kq][pxl][o4 * 4] =
                make_float4(acc[o4*4], acc[o4*4+1], acc[o4*4+2], acc[o4*4+3]);
    }
    __syncthreads();

    // reduce: thread = (pxl, oq); o_local = oq*4 + j
    {
        const int oq = tid >> 6;
        float4 s0 = *(const float4*)&part[0][pxl][oq * 4];
        float4 s1 = *(const float4*)&part[1][pxl][oq * 4];
        float4 s2 = *(const float4*)&part[2][pxl][oq * 4];
        float4 s3 = *(const float4*)&part[3][pxl][oq * 4];
        float v[4] = {s0.x + s1.x + s2.x + s3.x, s0.y + s1.y + s2.y + s3.y,
                      s0.z + s1.z + s2.z + s3.z, s0.w + s1.w + s2.w + s3.w};
        float* tb = t_out + (size_t)b * CR * HW + px0 + pxl;
#pragma unroll
        for (int j = 0; j < 4; j++) {
            int o = og * 16 + oq * 4 + j;
            tb[(size_t)o * HW] = fmaxf(v[j] + b1f[o], 0.f);
        }
    }
}

// k2: fused kernel-gen + involution for one (b, g, 4-row band).
// Phase A: thread=pixel, t (c-major) loaded once coalesced into tq[64] regs,
//          W2 via scalar loads -> w_lds[tap][px].
// Phase B: thread=(col-quad, row, 4-cg group), x streamed from global.
__global__ __launch_bounds__(256, 3) void k2_kgen_inv(
    const float* __restrict__ x, const float* __restrict__ t_in,
    const float* __restrict__ W2, const float* __restrict__ b2,
    float* __restrict__ out)
{
    __shared__ float w_lds[KK * WSTR];   // 44.7 KB -> 3 blocks/CU

    const int tid = threadIdx.x;
    const int band = blockIdx.x, g = blockIdx.y, b = blockIdx.z;
    const int h0 = band * RB;

    // ---------- phase A ----------
    if (tid < PXB) {
        float tq[64];
        {
            const float* tp = t_in + (size_t)b * CR * HW + h0 * HDIM + tid;
#pragma unroll 16
            for (int c = 0; c < CR; c++) tq[c] = tp[(size_t)c * HW];  // coalesced
        }
        const float* w2g = W2 + (size_t)g * KK * CR;
        const float* b2g = b2 + g * KK;
#pragma unroll 1
        for (int cc = 0; cc < 7; cc++) {      // 7 chunks of 7 taps
            float a[7];
#pragma unroll
            for (int i = 0; i < 7; i++) a[i] = b2g[cc * 7 + i];
#pragma unroll
            for (int c = 0; c < CR; c++) {
#pragma unroll
                for (int i = 0; i < 7; i++)
                    a[i] += tq[c] * w2g[(cc * 7 + i) * CR + c];  // s_load operand
            }
#pragma unroll
            for (int i = 0; i < 7; i++)
                w_lds[(cc * 7 + i) * WSTR + tid] = a[i];
        }
    }
    __syncthreads();

    // ---------- phase B: involution ----------
    if (tid < 224) {
        const int quad = tid % 14;          // output cols quad*4..+3
        const int tmp  = tid / 14;
        const int row  = tmp & 3;           // band-local row
        const int cgp  = tmp >> 2;          // channels cgp*4..+3
        const int colb = quad * 4;
        const int cb   = colb - 4;          // 12-col window base
        const int h    = h0 + row;
        const int px0  = row * HDIM + colb;
        const bool okL = quad > 0, okR = quad < 13;

        float acc[4][4];
#pragma unroll
        for (int i = 0; i < 4; i++)
#pragma unroll
            for (int k = 0; k < 4; k++) acc[i][k] = 0.f;

        const float* xg = x + ((size_t)b * CIN + g * CG + cgp * 4) * HW;
        const float4 z4 = make_float4(0.f, 0.f, 0.f, 0.f);

#pragma unroll 1
        for (int di = 0; di < 7; di++) {
            int hy = h + di - 3;
            bool rok = (hy >= 0) & (hy < HDIM);
            int hyc = min(max(hy, 0), HDIM - 1);
            float4 wv[7];
#pragma unroll
            for (int dj = 0; dj < 7; dj++)
                wv[dj] = *(const float4*)&w_lds[(di * 7 + dj) * WSTR + px0];

#pragma unroll 1
            for (int cgi = 0; cgi < 4; cgi++) {
                const float* xrow = xg + (size_t)cgi * HW + hyc * HDIM;
                float4 A  = (rok && okL) ? *(const float4*)&xrow[cb]     : z4;
                float4 Bv = rok          ? *(const float4*)&xrow[cb + 4] : z4;
                float4 Cv = (rok && okR) ? *(const float4*)&xrow[cb + 8] : z4;
                float win[12] = {A.x, A.y, A.z, A.w, Bv.x, Bv.y, Bv.z, Bv.w,
                                 Cv.x, Cv.y, Cv.z, Cv.w};
#pragma unroll
                for (int dj = 0; dj < 7; dj++) {
                    const float* wp = (const float*)&wv[dj];
#pragma unroll
                    for (int k = 0; k < 4; k++)
                        acc[cgi][k] += win[k + dj + 1] * wp[k];
                }
            }
        }

        float* op = out + ((size_t)b * CIN + g * CG + cgp * 4) * HW + h * HDIM + colb;
#pragma unroll
        for (int cgi = 0; cgi < 4; cgi++)
            *(float4*)&op[(size_t)cgi * HW] =
                make_float4(acc[cgi][0], acc[cgi][1], acc[cgi][2], acc[cgi][3]);
    }
}

extern "C" void kernel_launch(void* const* d_in, const int* in_sizes, int n_in,
                              void* d_out, int out_size, void* d_ws, size_t ws_size,
                              hipStream_t stream) {
    const float* x     = (const float*)d_in[0];
    const float* W1    = (const float*)d_in[1];
    const float* b1    = (const float*)d_in[2];
    const float* gamma = (const float*)d_in[3];
    const float* beta  = (const float*)d_in[4];
    const float* mean  = (const float*)d_in[5];
    const float* var   = (const float*)d_in[6];
    const float* W2    = (const float*)d_in[7];
    const float* b2    = (const float*)d_in[8];
    float* out = (float*)d_out;

    float* t_buf = (float*)d_ws;               // 4*64*3136 floats, [b][o][px]
    float* W1f   = t_buf + 4 * HW * CR;        // 16384 floats
    float* b1f   = W1f + CIN * CR;             // 64 floats

    k0_fold<<<CIN * CR / 256, 256, 0, stream>>>(W1, b1, gamma, beta, mean, var, W1f, b1f);

    dim3 g1(49, 4, 4);
    k1_conv<<<g1, 256, 0, stream>>>(x, W1f, b1f, t_buf);

    dim3 g2(NBAND, NG, 4);
    k2_kgen_inv<<<g2, 256, 0, stream>>>(x, t_buf, W2, b2, out);
}

// Round 5
// 229.255 us; speedup vs baseline: 1.1096x; 1.1096x over previous
//
#include <hip/hip_runtime.h>

#define HW    3136
#define HDIM  56
#define CIN   256
#define CR    64
#define NG    16
#define CG    16
#define KK    49
#define GK    784          // NG*KK
#define BEPS  1e-5f
#define RB    4            // rows per band in k2
#define NBAND 14           // 56 / RB
#define PXB   (RB * HDIM)  // 224 pixels per band
#define WSTR  228          // w_lds row stride (224 px + 4 pad)

// k0: fold BN into conv1 weights ([c][o] layout) and transpose W2 to
// W2T[c][g*49+tap] so phase-A scalar loads are contiguous per (g,c).
__global__ __launch_bounds__(256) void k0_fold(
    const float* __restrict__ W1, const float* __restrict__ b1,
    const float* __restrict__ gamma, const float* __restrict__ beta,
    const float* __restrict__ mean, const float* __restrict__ var,
    const float* __restrict__ W2,
    float* __restrict__ W1f, float* __restrict__ b1f, float* __restrict__ W2T)
{
    int idx = blockIdx.x * 256 + threadIdx.x;
    if (idx < CIN * CR) {                       // 16384: W1 fold+transpose
        int o = idx & 63, c = idx >> 6;
        float s = gamma[o] * rsqrtf(var[o] + BEPS);
        W1f[c * CR + o] = W1[o * CIN + c] * s;
        if (idx < CR) b1f[idx] = b1[idx] * s + beta[idx] - mean[idx] * s;
    }
    int jdx = idx - CIN * CR;
    if (jdx >= 0 && jdx < GK * CR) {            // 50176: W2 transpose
        int c = jdx & 63, gt = jdx >> 6;        // gt = g*49+tap
        W2T[c * GK + gt] = W2[gt * CR + c];
    }
}

// k1: t[b][o][px] = relu(x . W1f + b1f), c-major output. Stream-accumulate:
// thread = (pixel, 8-output group); a[8] in regs, x coalesced, W1f via s_load.
__global__ __launch_bounds__(256, 2) void k1_conv(
    const float* __restrict__ x, const float* __restrict__ W1f,
    const float* __restrict__ b1f, float* __restrict__ t_out)
{
    const int tid = threadIdx.x;
    const int pxl = tid & 63;
    const int og  = blockIdx.y * 4 + (tid >> 6);   // 0..7, wave-uniform
    const int b   = blockIdx.z;
    const int px  = blockIdx.x * 64 + pxl;

    float a[8];
#pragma unroll
    for (int j = 0; j < 8; j++) a[j] = b1f[og * 8 + j];

    const float* xb = x + (size_t)b * CIN * HW + px;
    const float* wb = W1f + og * 8;                 // + c*CR, wave-uniform
#pragma unroll 4
    for (int c = 0; c < CIN; c++) {
        float xv = xb[(size_t)c * HW];              // coalesced
        const float* wr = wb + c * CR;              // s_load_dwordx8
#pragma unroll
        for (int j = 0; j < 8; j++) a[j] += xv * wr[j];
    }
    float* tb = t_out + (size_t)b * CR * HW + px;
#pragma unroll
    for (int j = 0; j < 8; j++)
        tb[(size_t)(og * 8 + j) * HW] = fmaxf(a[j], 0.f);
}

// k2: fused kernel-gen + involution for one (b, g, 4-row band).
// Phase A: stream-accumulate — a[49] in regs, t streamed (1 coalesced dword
//          per c), W2T row via contiguous s_load. No large input cache.
// Phase B: thread=(col-quad, row, 4-cg group), x streamed from global.
__global__ __launch_bounds__(256, 2) void k2_kgen_inv(
    const float* __restrict__ x, const float* __restrict__ t_in,
    const float* __restrict__ W2T, const float* __restrict__ b2,
    float* __restrict__ out)
{
    __shared__ float w_lds[KK * WSTR];   // 44.7 KB -> 3 blocks/CU

    const int tid = threadIdx.x;
    const int band = blockIdx.x, g = blockIdx.y, b = blockIdx.z;
    const int h0 = band * RB;

    // ---------- phase A ----------
    if (tid < PXB) {
        float a[49];
        const float* b2g = b2 + g * KK;
#pragma unroll
        for (int i = 0; i < KK; i++) a[i] = b2g[i];

        const float* tp  = t_in + (size_t)b * CR * HW + h0 * HDIM + tid;
        const float* w2t = W2T + g * KK;            // + c*GK, wave-uniform
#pragma unroll 2
        for (int c = 0; c < CR; c++) {
            float tv = tp[(size_t)c * HW];          // coalesced, L2-hot
            const float* wr = w2t + c * GK;         // 49 contiguous -> s_load
#pragma unroll
            for (int i = 0; i < KK; i++) a[i] += tv * wr[i];
        }
#pragma unroll
        for (int i = 0; i < KK; i++)
            w_lds[i * WSTR + tid] = a[i];
    }
    __syncthreads();

    // ---------- phase B: involution ----------
    if (tid < 224) {
        const int quad = tid % 14;          // output cols quad*4..+3
        const int tmp  = tid / 14;
        const int row  = tmp & 3;           // band-local row
        const int cgp  = tmp >> 2;          // channels cgp*4..+3
        const int colb = quad * 4;
        const int cb   = colb - 4;          // 12-col window base
        const int h    = h0 + row;
        const int px0  = row * HDIM + colb;
        const bool okL = quad > 0, okR = quad < 13;

        float acc[4][4];
#pragma unroll
        for (int i = 0; i < 4; i++)
#pragma unroll
            for (int k = 0; k < 4; k++) acc[i][k] = 0.f;

        const float* xg = x + ((size_t)b * CIN + g * CG + cgp * 4) * HW;
        const float4 z4 = make_float4(0.f, 0.f, 0.f, 0.f);

#pragma unroll 1
        for (int di = 0; di < 7; di++) {
            int hy = h + di - 3;
            bool rok = (hy >= 0) & (hy < HDIM);
            int hyc = min(max(hy, 0), HDIM - 1);
            float4 wv[7];
#pragma unroll
            for (int dj = 0; dj < 7; dj++)
                wv[dj] = *(const float4*)&w_lds[(di * 7 + dj) * WSTR + px0];

#pragma unroll 1
            for (int cgi = 0; cgi < 4; cgi++) {
                const float* xrow = xg + (size_t)cgi * HW + hyc * HDIM;
                float4 A  = (rok && okL) ? *(const float4*)&xrow[cb]     : z4;
                float4 Bv = rok          ? *(const float4*)&xrow[cb + 4] : z4;
                float4 Cv = (rok && okR) ? *(const float4*)&xrow[cb + 8] : z4;
                float win[12] = {A.x, A.y, A.z, A.w, Bv.x, Bv.y, Bv.z, Bv.w,
                                 Cv.x, Cv.y, Cv.z, Cv.w};
#pragma unroll
                for (int dj = 0; dj < 7; dj++) {
                    const float* wp = (const float*)&wv[dj];
#pragma unroll
                    for (int k = 0; k < 4; k++)
                        acc[cgi][k] += win[k + dj + 1] * wp[k];
                }
            }
        }

        float* op = out + ((size_t)b * CIN + g * CG + cgp * 4) * HW + h * HDIM + colb;
#pragma unroll
        for (int cgi = 0; cgi < 4; cgi++)
            *(float4*)&op[(size_t)cgi * HW] =
                make_float4(acc[cgi][0], acc[cgi][1], acc[cgi][2], acc[cgi][3]);
    }
}

extern "C" void kernel_launch(void* const* d_in, const int* in_sizes, int n_in,
                              void* d_out, int out_size, void* d_ws, size_t ws_size,
                              hipStream_t stream) {
    const float* x     = (const float*)d_in[0];
    const float* W1    = (const float*)d_in[1];
    const float* b1    = (const float*)d_in[2];
    const float* gamma = (const float*)d_in[3];
    const float* beta  = (const float*)d_in[4];
    const float* mean  = (const float*)d_in[5];
    const float* var   = (const float*)d_in[6];
    const float* W2    = (const float*)d_in[7];
    const float* b2    = (const float*)d_in[8];
    float* out = (float*)d_out;

    float* t_buf = (float*)d_ws;               // 4*64*3136 floats, [b][o][px]
    float* W1f   = t_buf + 4 * HW * CR;        // 16384 floats
    float* b1f   = W1f + CIN * CR;             // 64 floats
    float* W2T   = b1f + CR;                   // 50176 floats (total ~3.47 MB)

    int n_k0 = CIN * CR + GK * CR;             // 66560 elements
    k0_fold<<<(n_k0 + 255) / 256, 256, 0, stream>>>(
        W1, b1, gamma, beta, mean, var, W2, W1f, b1f, W2T);

    dim3 g1(49, 2, 4);
    k1_conv<<<g1, 256, 0, stream>>>(x, W1f, b1f, t_buf);

    dim3 g2(NBAND, NG, 4);
    k2_kgen_inv<<<g2, 256, 0, stream>>>(x, t_buf, W2T, b2, out);
}

// Round 6
// 145.351 us; speedup vs baseline: 1.7501x; 1.5772x over previous
//
#include <hip/hip_runtime.h>

#define HW    3136
#define HDIM  56
#define CIN   256
#define CR    64
#define NG    16
#define KK    49
#define BEPS  1e-5f
#define RB    4
#define NBAND 14
#define PXB   224          // pixels per band
#define WSTR  228          // w_lds row stride

typedef __attribute__((ext_vector_type(8))) short short8;
typedef __attribute__((ext_vector_type(4))) float f32x4;

__device__ __forceinline__ unsigned short f2bf(float f) {
    union { float f; unsigned u; } v; v.f = f;
    unsigned r = (v.u + 0x7FFFu + ((v.u >> 16) & 1u)) >> 16;
    return (unsigned short)r;
}

// k0: W1b[o][c] = bf16(W1*scale)  (64x256, row-major, = B^T layout for k1)
//     W2bT[g][tap(pad 64)][c] = bf16(W2)  (B^T layout for k2 phase A)
//     b1f[o] = b1*s + beta - mean*s
__global__ __launch_bounds__(256) void k0_prep(
    const float* __restrict__ W1, const float* __restrict__ b1,
    const float* __restrict__ gamma, const float* __restrict__ beta,
    const float* __restrict__ mean, const float* __restrict__ var,
    const float* __restrict__ W2,
    unsigned short* __restrict__ W1b, unsigned short* __restrict__ W2bT,
    float* __restrict__ b1f)
{
    int idx = blockIdx.x * 256 + threadIdx.x;
    if (idx < CR * CIN) {                              // 16384
        int o = idx >> 8;
        float s = gamma[o] * rsqrtf(var[o] + BEPS);
        W1b[idx] = f2bf(W1[idx] * s);
    } else if (idx < CR * CIN + NG * 64 * 64) {        // + 65536
        int j = idx - CR * CIN;
        int c = j & 63, tap = (j >> 6) & 63, g = j >> 12;
        float v = (tap < KK) ? W2[(g * KK + tap) * CR + c] : 0.f;
        W2bT[j] = f2bf(v);
    } else if (idx < CR * CIN + NG * 64 * 64 + CR) {
        int o = idx - CR * CIN - NG * 64 * 64;
        float s = gamma[o] * rsqrtf(var[o] + BEPS);
        b1f[o] = b1[o] * s + beta[o] - mean[o] * s;
    }
}

// k1: conv1 as MFMA GEMM. Block = 64 px x 64 outs; wave w = M-tile w.
// x staged per 64-c chunk into LDS as bf16 in A-frag-friendly layout.
// Output t_bf[b][px][64] bf16 (relu applied) — exactly the A-layout k2 needs.
__global__ __launch_bounds__(256) void k1_gemm(
    const float* __restrict__ x, const unsigned short* __restrict__ W1b,
    const float* __restrict__ b1f, unsigned short* __restrict__ t_bf)
{
    __shared__ unsigned short x_a[64 * 72];   // [px][c+pad] 18.4 KB

    const int tid = threadIdx.x;
    const int b = blockIdx.y;
    const int px0 = blockIdx.x * 64;
    const int lane = tid & 63, l15 = lane & 15, q = lane >> 4;
    const int wid = tid >> 6;

    f32x4 acc[4];
#pragma unroll
    for (int nt = 0; nt < 4; nt++) acc[nt] = (f32x4){0.f, 0.f, 0.f, 0.f};

    for (int kc = 0; kc < 4; kc++) {
        __syncthreads();
        {   // stage 64c x 64px chunk, coalesced (lane = px)
            int pxl = tid & 63, cs = tid >> 6;
#pragma unroll
            for (int i = 0; i < 16; i++) {
                int cl = cs * 16 + i;
                float xv = x[((size_t)b * CIN + kc * 64 + cl) * HW + px0 + pxl];
                x_a[pxl * 72 + cl] = f2bf(xv);
            }
        }
        __syncthreads();
#pragma unroll
        for (int ks = 0; ks < 2; ks++) {
            short8 af = *(const short8*)&x_a[(16 * wid + l15) * 72 + ks * 32 + q * 8];
#pragma unroll
            for (int nt = 0; nt < 4; nt++) {
                short8 bf = *(const short8*)&W1b[(size_t)(16 * nt + l15) * CIN + kc * 64 + ks * 32 + q * 8];
                acc[nt] = __builtin_amdgcn_mfma_f32_16x16x32_bf16(af, bf, acc[nt], 0, 0, 0);
            }
        }
    }
#pragma unroll
    for (int nt = 0; nt < 4; nt++) {
        float bias = b1f[16 * nt + l15];
#pragma unroll
        for (int r = 0; r < 4; r++) {
            int px = px0 + 16 * wid + 4 * q + r;     // D: m = 4*quad + reg
            float v = fmaxf(acc[nt][r] + bias, 0.f);
            t_bf[((size_t)b * HW + px) * CR + 16 * nt + l15] = f2bf(v);
        }
    }
}

// k2: fused kernel-gen (MFMA) + involution for one (b, g, band, cg-half).
// Phase A: M=224 px (14 tiles), N=49->64 taps, K=64; A-frags direct from t_bf,
//          B-frags from W2bT; D written to w_lds[tap][px].
// Phase B: x tile (8cg x 10rows x 68cols, borders pre-zeroed) in LDS; no masks.
__global__ __launch_bounds__(256, 2) void k2_fused(
    const float* __restrict__ x, const unsigned short* __restrict__ t_bf,
    const unsigned short* __restrict__ W2bT, const float* __restrict__ b2,
    float* __restrict__ out)
{
    __shared__ float w_lds[KK * WSTR];      // 44.7 KB
    __shared__ float x_lds[8 * 10 * 68];    // 21.8 KB  (total 66.4 KB -> 2/CU)

    const int tid = threadIdx.x;
    const int band = blockIdx.x, g = blockIdx.y;
    const int b = blockIdx.z >> 1, half = blockIdx.z & 1;
    const int h0 = band * RB;
    const int lane = tid & 63, l15 = lane & 15, q = lane >> 4;
    const int wid = tid >> 6;

    // ---- stage x tile (zero-padded: cols 0..3 / 60..67, OOB rows) ----
    for (int i = tid; i < 8 * 10 * 68; i += 256) {
        int col = i % 68; int t2 = i / 68; int row = t2 % 10; int cg = t2 / 10;
        int hy = h0 - 3 + row, xc = col - 4;
        float v = 0.f;
        if (hy >= 0 && hy < HDIM && xc >= 0 && xc < HDIM)
            v = x[((size_t)b * CIN + g * 16 + half * 8 + cg) * HW + hy * HDIM + xc];
        x_lds[i] = v;
    }

    // ---- phase A: MFMA kernel-gen ----
    {
        short8 bfr[4][2];
#pragma unroll
        for (int nt = 0; nt < 4; nt++)
#pragma unroll
            for (int ks = 0; ks < 2; ks++)
                bfr[nt][ks] = *(const short8*)&W2bT[((size_t)g * 64 + 16 * nt + l15) * 64 + ks * 32 + q * 8];
        float b2v[4];
#pragma unroll
        for (int nt = 0; nt < 4; nt++) {
            int tap = 16 * nt + l15;
            b2v[nt] = (tap < KK) ? b2[g * KK + tap] : 0.f;
        }
        for (int mt = wid; mt < 14; mt += 4) {
            const unsigned short* tp = &t_bf[((size_t)b * HW + h0 * HDIM + mt * 16 + l15) * CR];
            short8 a0 = *(const short8*)&tp[q * 8];
            short8 a1 = *(const short8*)&tp[32 + q * 8];
#pragma unroll
            for (int nt = 0; nt < 4; nt++) {
                f32x4 acc = (f32x4){0.f, 0.f, 0.f, 0.f};
                acc = __builtin_amdgcn_mfma_f32_16x16x32_bf16(a0, bfr[nt][0], acc, 0, 0, 0);
                acc = __builtin_amdgcn_mfma_f32_16x16x32_bf16(a1, bfr[nt][1], acc, 0, 0, 0);
                int tap = 16 * nt + l15;
                if (tap < KK) {
#pragma unroll
                    for (int r = 0; r < 4; r++)
                        w_lds[tap * WSTR + mt * 16 + 4 * q + r] = acc[r] + b2v[nt];
                }
            }
        }
    }
    __syncthreads();

    // ---- phase B: involution from LDS, no masking ----
    if (tid < PXB) {
        const int quad = tid % 14, rem = tid / 14;
        const int row = rem & 3, cgp = rem >> 2;
        const int colb = quad * 4, h = h0 + row;

        float acc[2][4];
#pragma unroll
        for (int i = 0; i < 2; i++)
#pragma unroll
            for (int k = 0; k < 4; k++) acc[i][k] = 0.f;

#pragma unroll
        for (int di = 0; di < 7; di++) {
            int rowl = row + di;
            float wv[7][4];
#pragma unroll
            for (int dj = 0; dj < 7; dj++) {
                float4 wq = *(const float4*)&w_lds[(di * 7 + dj) * WSTR + row * HDIM + colb];
                wv[dj][0] = wq.x; wv[dj][1] = wq.y; wv[dj][2] = wq.z; wv[dj][3] = wq.w;
            }
#pragma unroll
            for (int cgi = 0; cgi < 2; cgi++) {
                const float* xr = &x_lds[((cgp * 2 + cgi) * 10 + rowl) * 68 + colb];
                float4 A  = *(const float4*)&xr[0];
                float4 Bv = *(const float4*)&xr[4];
                float4 Cv = *(const float4*)&xr[8];
                float win[12] = {A.x, A.y, A.z, A.w, Bv.x, Bv.y, Bv.z, Bv.w,
                                 Cv.x, Cv.y, Cv.z, Cv.w};
#pragma unroll
                for (int dj = 0; dj < 7; dj++)
#pragma unroll
                    for (int kk = 0; kk < 4; kk++)
                        acc[cgi][kk] += win[kk + dj + 1] * wv[dj][kk];
            }
        }
#pragma unroll
        for (int cgi = 0; cgi < 2; cgi++) {
            float* op = &out[((size_t)b * CIN + g * 16 + half * 8 + cgp * 2 + cgi) * HW + h * HDIM + colb];
            *(float4*)op = make_float4(acc[cgi][0], acc[cgi][1], acc[cgi][2], acc[cgi][3]);
        }
    }
}

extern "C" void kernel_launch(void* const* d_in, const int* in_sizes, int n_in,
                              void* d_out, int out_size, void* d_ws, size_t ws_size,
                              hipStream_t stream) {
    const float* x     = (const float*)d_in[0];
    const float* W1    = (const float*)d_in[1];
    const float* b1    = (const float*)d_in[2];
    const float* gamma = (const float*)d_in[3];
    const float* beta  = (const float*)d_in[4];
    const float* mean  = (const float*)d_in[5];
    const float* var   = (const float*)d_in[6];
    const float* W2    = (const float*)d_in[7];
    const float* b2    = (const float*)d_in[8];
    float* out = (float*)d_out;

    unsigned short* t_bf = (unsigned short*)d_ws;          // 802816 ushorts
    unsigned short* W1b  = t_bf + (size_t)4 * HW * CR;     // 16384
    unsigned short* W2bT = W1b + CR * CIN;                 // 65536
    float* b1f           = (float*)(W2bT + NG * 64 * 64);  // 64  (total 1.77 MB)

    int n_k0 = CR * CIN + NG * 64 * 64 + CR;
    k0_prep<<<(n_k0 + 255) / 256, 256, 0, stream>>>(
        W1, b1, gamma, beta, mean, var, W2, W1b, W2bT, b1f);

    dim3 g1(HW / 64, 4);
    k1_gemm<<<g1, 256, 0, stream>>>(x, W1b, b1f, t_bf);

    dim3 g2(NBAND, NG, 8);
    k2_fused<<<g2, 256, 0, stream>>>(x, t_bf, W2bT, b2, out);
}

// Round 7
// 136.159 us; speedup vs baseline: 1.8682x; 1.0675x over previous
//
#include <hip/hip_runtime.h>

#define HW    3136
#define HDIM  56
#define CIN   256
#define CR    64
#define NG    16
#define KK    49
#define BEPS  1e-5f
#define RB    2            // output rows per k2 band
#define NBAND 28           // 56 / RB
#define WSTR  116          // RB*56 + 4, float stride, 16B-aligned, near-uniform banks
#define XROWS 8            // RB + 6 halo rows
#define XSTR  68           // 56 + 2*4 padded cols, pre-zeroed borders

typedef __attribute__((ext_vector_type(8))) short short8;
typedef __attribute__((ext_vector_type(4))) float f32x4;

__device__ __forceinline__ unsigned short f2bf(float f) {
    union { float f; unsigned u; } v; v.f = f;
    unsigned r = (v.u + 0x7FFFu + ((v.u >> 16) & 1u)) >> 16;
    return (unsigned short)r;
}

// k0: W1b[o][c]=bf16(W1*scale) (B^T layout for k1); W2bT[g][tap pad64][c]=bf16(W2)
//     (B^T layout for k2 phase A); b1f = folded BN bias.
__global__ __launch_bounds__(256) void k0_prep(
    const float* __restrict__ W1, const float* __restrict__ b1,
    const float* __restrict__ gamma, const float* __restrict__ beta,
    const float* __restrict__ mean, const float* __restrict__ var,
    const float* __restrict__ W2,
    unsigned short* __restrict__ W1b, unsigned short* __restrict__ W2bT,
    float* __restrict__ b1f)
{
    int idx = blockIdx.x * 256 + threadIdx.x;
    if (idx < CR * CIN) {
        int o = idx >> 8;
        float s = gamma[o] * rsqrtf(var[o] + BEPS);
        W1b[idx] = f2bf(W1[idx] * s);
    } else if (idx < CR * CIN + NG * 64 * 64) {
        int j = idx - CR * CIN;
        int c = j & 63, tap = (j >> 6) & 63, g = j >> 12;
        float v = (tap < KK) ? W2[(g * KK + tap) * CR + c] : 0.f;
        W2bT[j] = f2bf(v);
    } else if (idx < CR * CIN + NG * 64 * 64 + CR) {
        int o = idx - CR * CIN - NG * 64 * 64;
        float s = gamma[o] * rsqrtf(var[o] + BEPS);
        b1f[o] = b1[o] * s + beta[o] - mean[o] * s;
    }
}

// k1: conv1 MFMA, LDS-free. Wave = 16px M-tile x 64 outs, K=256.
// A-frags built from global x (coalesced px across l15), B-frags from L2-hot W1b.
// Output t_bf[b][px][64] bf16 with relu — the A-layout k2 phase A consumes.
__global__ __launch_bounds__(256) void k1_gemm(
    const float* __restrict__ x, const unsigned short* __restrict__ W1b,
    const float* __restrict__ b1f, unsigned short* __restrict__ t_bf)
{
    const int tid = threadIdx.x;
    const int b = blockIdx.y;
    const int lane = tid & 63, l15 = lane & 15, q = lane >> 4;
    const int wid = tid >> 6;
    const int pxb = blockIdx.x * 64 + wid * 16;    // wave's M-base

    const float* xp = x + (size_t)b * CIN * HW + pxb + l15;

    f32x4 acc[4];
#pragma unroll
    for (int nt = 0; nt < 4; nt++) acc[nt] = (f32x4){0.f, 0.f, 0.f, 0.f};

#pragma unroll 2
    for (int kc = 0; kc < 8; kc++) {               // K chunks of 32
        short8 af;
#pragma unroll
        for (int j = 0; j < 8; j++) {
            float xv = xp[(size_t)(kc * 32 + q * 8 + j) * HW];
            af[j] = (short)f2bf(xv);
        }
#pragma unroll
        for (int nt = 0; nt < 4; nt++) {
            short8 bf = *(const short8*)&W1b[(size_t)(16 * nt + l15) * CIN + kc * 32 + q * 8];
            acc[nt] = __builtin_amdgcn_mfma_f32_16x16x32_bf16(af, bf, acc[nt], 0, 0, 0);
        }
    }
#pragma unroll
    for (int nt = 0; nt < 4; nt++) {
        float bias = b1f[16 * nt + l15];
#pragma unroll
        for (int r = 0; r < 4; r++) {
            int px = pxb + 4 * q + r;              // D: m = 4*quad + reg
            float v = fmaxf(acc[nt][r] + bias, 0.f);
            t_bf[((size_t)b * HW + px) * CR + 16 * nt + l15] = f2bf(v);
        }
    }
}

// k2: fused kernel-gen (MFMA) + involution for one (b, g, 2-row band, cg-half).
// LDS = 40.1 KB -> 4 blocks/CU. Phase-A D-stores are float4 (minimal bank passes).
__global__ __launch_bounds__(256, 4) void k2_fused(
    const float* __restrict__ x, const unsigned short* __restrict__ t_bf,
    const unsigned short* __restrict__ W2bT, const float* __restrict__ b2,
    float* __restrict__ out)
{
    __shared__ float w_lds[KK * WSTR];            // 22.7 KB
    __shared__ float x_lds[8 * XROWS * XSTR];     // 17.4 KB, borders pre-zeroed

    const int tid = threadIdx.x;
    const int band = blockIdx.x, g = blockIdx.y;
    const int b = blockIdx.z >> 1, half = blockIdx.z & 1;
    const int h0 = band * RB;
    const int lane = tid & 63, l15 = lane & 15, q = lane >> 4;
    const int wid = tid >> 6;

    // ---- stage x tile (8 ch x 8 rows x 68 cols, zero-padded) ----
    for (int i = tid; i < 8 * XROWS * XSTR; i += 256) {
        int col = i % XSTR; int t2 = i / XSTR; int row = t2 % XROWS; int cg = t2 / XROWS;
        int hy = h0 - 3 + row, xc = col - 4;
        float v = 0.f;
        if (hy >= 0 && hy < HDIM && xc >= 0 && xc < HDIM)
            v = x[((size_t)b * CIN + g * 16 + half * 8 + cg) * HW + hy * HDIM + xc];
        x_lds[i] = v;
    }

    // ---- phase A: kgen MFMA, M=112 px (7 tiles), N=64 taps, K=64 ----
    {
        short8 bfr[4][2];
#pragma unroll
        for (int nt = 0; nt < 4; nt++)
#pragma unroll
            for (int ks = 0; ks < 2; ks++)
                bfr[nt][ks] = *(const short8*)&W2bT[((size_t)g * 64 + 16 * nt + l15) * 64 + ks * 32 + q * 8];
        float b2v[4];
#pragma unroll
        for (int nt = 0; nt < 4; nt++) {
            int tap = 16 * nt + l15;
            b2v[nt] = (tap < KK) ? b2[g * KK + tap] : 0.f;
        }
        for (int mt = wid; mt < 7; mt += 4) {
            const unsigned short* tp = &t_bf[((size_t)b * HW + h0 * HDIM + mt * 16 + l15) * CR];
            short8 a0 = *(const short8*)&tp[q * 8];
            short8 a1 = *(const short8*)&tp[32 + q * 8];
#pragma unroll
            for (int nt = 0; nt < 4; nt++) {
                f32x4 acc = (f32x4){0.f, 0.f, 0.f, 0.f};
                acc = __builtin_amdgcn_mfma_f32_16x16x32_bf16(a0, bfr[nt][0], acc, 0, 0, 0);
                acc = __builtin_amdgcn_mfma_f32_16x16x32_bf16(a1, bfr[nt][1], acc, 0, 0, 0);
                int tap = 16 * nt + l15;
                if (tap < KK) {
                    *(float4*)&w_lds[tap * WSTR + mt * 16 + 4 * q] =
                        make_float4(acc[0] + b2v[nt], acc[1] + b2v[nt],
                                    acc[2] + b2v[nt], acc[3] + b2v[nt]);
                }
            }
        }
    }
    __syncthreads();

    // ---- phase B: involution from LDS, no masking ----
    if (tid < 224) {
        const int quad = tid % 14, rem = tid / 14;
        const int row = rem & 1, cg = rem >> 1;    // 2 rows x 8 ch
        const int colb = quad * 4, h = h0 + row;

        float acc[4] = {0.f, 0.f, 0.f, 0.f};

#pragma unroll
        for (int di = 0; di < 7; di++) {
            float wv[7][4];
#pragma unroll
            for (int dj = 0; dj < 7; dj++) {
                float4 wq = *(const float4*)&w_lds[(di * 7 + dj) * WSTR + row * HDIM + colb];
                wv[dj][0] = wq.x; wv[dj][1] = wq.y; wv[dj][2] = wq.z; wv[dj][3] = wq.w;
            }
            const float* xr = &x_lds[(cg * XROWS + row + di) * XSTR + colb];
            float4 A  = *(const float4*)&xr[0];
            float4 Bv = *(const float4*)&xr[4];
            float4 Cv = *(const float4*)&xr[8];
            float win[12] = {A.x, A.y, A.z, A.w, Bv.x, Bv.y, Bv.z, Bv.w,
                             Cv.x, Cv.y, Cv.z, Cv.w};
#pragma unroll
            for (int dj = 0; dj < 7; dj++)
#pragma unroll
                for (int kk = 0; kk < 4; kk++)
                    acc[kk] += win[kk + dj + 1] * wv[dj][kk];
        }
        float* op = &out[((size_t)b * CIN + g * 16 + half * 8 + cg) * HW + h * HDIM + colb];
        *(float4*)op = make_float4(acc[0], acc[1], acc[2], acc[3]);
    }
}

extern "C" void kernel_launch(void* const* d_in, const int* in_sizes, int n_in,
                              void* d_out, int out_size, void* d_ws, size_t ws_size,
                              hipStream_t stream) {
    const float* x     = (const float*)d_in[0];
    const float* W1    = (const float*)d_in[1];
    const float* b1    = (const float*)d_in[2];
    const float* gamma = (const float*)d_in[3];
    const float* beta  = (const float*)d_in[4];
    const float* mean  = (const float*)d_in[5];
    const float* var   = (const float*)d_in[6];
    const float* W2    = (const float*)d_in[7];
    const float* b2    = (const float*)d_in[8];
    float* out = (float*)d_out;

    unsigned short* t_bf = (unsigned short*)d_ws;          // 802816 ushorts
    unsigned short* W1b  = t_bf + (size_t)4 * HW * CR;     // 16384
    unsigned short* W2bT = W1b + CR * CIN;                 // 65536
    float* b1f           = (float*)(W2bT + NG * 64 * 64);  // 64

    int n_k0 = CR * CIN + NG * 64 * 64 + CR;
    k0_prep<<<(n_k0 + 255) / 256, 256, 0, stream>>>(
        W1, b1, gamma, beta, mean, var, W2, W1b, W2bT, b1f);

    dim3 g1(HW / 64, 4);
    k1_gemm<<<g1, 256, 0, stream>>>(x, W1b, b1f, t_bf);

    dim3 g2(NBAND, NG, 8);
    k2_fused<<<g2, 256, 0, stream>>>(x, t_bf, W2bT, b2, out);
}

// Round 8
// 133.704 us; speedup vs baseline: 1.9025x; 1.0184x over previous
//
#include <hip/hip_runtime.h>

#define HW    3136
#define HDIM  56
#define CIN   256
#define CR    64
#define NG    16
#define KK    49
#define BEPS  1e-5f
#define RB    2            // output rows per k2 band
#define NBAND 28           // 56 / RB
#define WSTR  116          // RB*56 + 4 floats
#define XROWS 8            // RB + 6 halo rows
#define XSTR  68           // 56 + 2*4 padded cols, pre-zeroed borders

typedef __attribute__((ext_vector_type(8))) short short8;
typedef __attribute__((ext_vector_type(4))) float f32x4;

__device__ __forceinline__ unsigned short f2bf(float f) {
    union { float f; unsigned u; } v; v.f = f;
    unsigned r = (v.u + 0x7FFFu + ((v.u >> 16) & 1u)) >> 16;
    return (unsigned short)r;
}

// k0: W1b[o][c]=bf16(W1*scale) (B^T for k1); W2bT[g][tap pad64][c]=bf16(W2)
//     (B^T for k2 phase A); b1f = folded BN bias.
__global__ __launch_bounds__(256) void k0_prep(
    const float* __restrict__ W1, const float* __restrict__ b1,
    const float* __restrict__ gamma, const float* __restrict__ beta,
    const float* __restrict__ mean, const float* __restrict__ var,
    const float* __restrict__ W2,
    unsigned short* __restrict__ W1b, unsigned short* __restrict__ W2bT,
    float* __restrict__ b1f)
{
    int idx = blockIdx.x * 256 + threadIdx.x;
    if (idx < CR * CIN) {
        int o = idx >> 8;
        float s = gamma[o] * rsqrtf(var[o] + BEPS);
        W1b[idx] = f2bf(W1[idx] * s);
    } else if (idx < CR * CIN + NG * 64 * 64) {
        int j = idx - CR * CIN;
        int c = j & 63, tap = (j >> 6) & 63, g = j >> 12;
        float v = (tap < KK) ? W2[(g * KK + tap) * CR + c] : 0.f;
        W2bT[j] = f2bf(v);
    } else if (idx < CR * CIN + NG * 64 * 64 + CR) {
        int o = idx - CR * CIN - NG * 64 * 64;
        float s = gamma[o] * rsqrtf(var[o] + BEPS);
        b1f[o] = b1[o] * s + beta[o] - mean[o] * s;
    }
}

// k1: conv1 MFMA, LDS-free. Wave = 16px M-tile x 64 outs, K=256.
__global__ __launch_bounds__(256) void k1_gemm(
    const float* __restrict__ x, const unsigned short* __restrict__ W1b,
    const float* __restrict__ b1f, unsigned short* __restrict__ t_bf)
{
    const int tid = threadIdx.x;
    const int b = blockIdx.y;
    const int lane = tid & 63, l15 = lane & 15, q = lane >> 4;
    const int wid = tid >> 6;
    const int pxb = blockIdx.x * 64 + wid * 16;

    const float* xp = x + (size_t)b * CIN * HW + pxb + l15;

    f32x4 acc[4];
#pragma unroll
    for (int nt = 0; nt < 4; nt++) acc[nt] = (f32x4){0.f, 0.f, 0.f, 0.f};

#pragma unroll 2
    for (int kc = 0; kc < 8; kc++) {
        short8 af;
#pragma unroll
        for (int j = 0; j < 8; j++) {
            float xv = xp[(size_t)(kc * 32 + q * 8 + j) * HW];
            af[j] = (short)f2bf(xv);
        }
#pragma unroll
        for (int nt = 0; nt < 4; nt++) {
            short8 bf = *(const short8*)&W1b[(size_t)(16 * nt + l15) * CIN + kc * 32 + q * 8];
            acc[nt] = __builtin_amdgcn_mfma_f32_16x16x32_bf16(af, bf, acc[nt], 0, 0, 0);
        }
    }
#pragma unroll
    for (int nt = 0; nt < 4; nt++) {
        float bias = b1f[16 * nt + l15];
#pragma unroll
        for (int r = 0; r < 4; r++) {
            int px = pxb + 4 * q + r;
            float v = fmaxf(acc[nt][r] + bias, 0.f);
            t_bf[((size_t)b * HW + px) * CR + 16 * nt + l15] = f2bf(v);
        }
    }
}

// k2: fused kernel-gen (MFMA) + involution for one (b, g, 2-row band, cg-half).
// Phase-B mapping: tid = quad*16 + row*8 + cg -> w_lds reads are 8-way
// same-address broadcasts within a wave; x_lds [rowx][cg][col] is bank-balanced.
__global__ __launch_bounds__(256, 4) void k2_fused(
    const float* __restrict__ x, const unsigned short* __restrict__ t_bf,
    const unsigned short* __restrict__ W2bT, const float* __restrict__ b2,
    float* __restrict__ out)
{
    __shared__ float w_lds[KK * WSTR];               // 22.7 KB
    __shared__ float x_lds[XROWS * 8 * XSTR];        // 17.4 KB  (40.1 KB -> 4/CU)

    const int tid = threadIdx.x;
    const int band = blockIdx.x, g = blockIdx.y;
    const int b = blockIdx.z >> 1, half = blockIdx.z & 1;
    const int h0 = band * RB;
    const int lane = tid & 63, l15 = lane & 15, q = lane >> 4;
    const int wid = tid >> 6;

    // ---- stage x tile: layout [rowx][cg][col], zero-padded borders ----
    for (int i = tid; i < XROWS * 8 * XSTR; i += 256) {
        int col = i % XSTR; int t2 = i / XSTR; int cg = t2 & 7; int rowx = t2 >> 3;
        int hy = h0 - 3 + rowx, xc = col - 4;
        float v = 0.f;
        if (hy >= 0 && hy < HDIM && xc >= 0 && xc < HDIM)
            v = x[((size_t)b * CIN + g * 16 + half * 8 + cg) * HW + hy * HDIM + xc];
        x_lds[i] = v;
    }

    // ---- phase A: kgen MFMA, M=112 px (7 tiles), N=64 taps, K=64 ----
    {
        short8 bfr[4][2];
#pragma unroll
        for (int nt = 0; nt < 4; nt++)
#pragma unroll
            for (int ks = 0; ks < 2; ks++)
                bfr[nt][ks] = *(const short8*)&W2bT[((size_t)g * 64 + 16 * nt + l15) * 64 + ks * 32 + q * 8];
        float b2v[4];
#pragma unroll
        for (int nt = 0; nt < 4; nt++) {
            int tap = 16 * nt + l15;
            b2v[nt] = (tap < KK) ? b2[g * KK + tap] : 0.f;
        }
        for (int mt = wid; mt < 7; mt += 4) {
            const unsigned short* tp = &t_bf[((size_t)b * HW + h0 * HDIM + mt * 16 + l15) * CR];
            short8 a0 = *(const short8*)&tp[q * 8];
            short8 a1 = *(const short8*)&tp[32 + q * 8];
#pragma unroll
            for (int nt = 0; nt < 4; nt++) {
                f32x4 acc = (f32x4){0.f, 0.f, 0.f, 0.f};
                acc = __builtin_amdgcn_mfma_f32_16x16x32_bf16(a0, bfr[nt][0], acc, 0, 0, 0);
                acc = __builtin_amdgcn_mfma_f32_16x16x32_bf16(a1, bfr[nt][1], acc, 0, 0, 0);
                int tap = 16 * nt + l15;
                if (tap < KK) {
                    *(float4*)&w_lds[tap * WSTR + mt * 16 + 4 * q] =
                        make_float4(acc[0] + b2v[nt], acc[1] + b2v[nt],
                                    acc[2] + b2v[nt], acc[3] + b2v[nt]);
                }
            }
        }
    }
    __syncthreads();

    // ---- phase B: involution. tid = quad*16 + row*8 + cg ----
    if (tid < 224) {
        const int quad = tid >> 4;          // 0..13
        const int rem  = tid & 15;
        const int row  = rem >> 3;          // 0..1
        const int cg   = rem & 7;           // 0..7
        const int colb = quad * 4, h = h0 + row;

        float acc[4] = {0.f, 0.f, 0.f, 0.f};

#pragma unroll
        for (int di = 0; di < 7; di++) {
            float wv[7][4];
#pragma unroll
            for (int dj = 0; dj < 7; dj++) {
                float4 wq = *(const float4*)&w_lds[(di * 7 + dj) * WSTR + row * HDIM + colb];
                wv[dj][0] = wq.x; wv[dj][1] = wq.y; wv[dj][2] = wq.z; wv[dj][3] = wq.w;
            }
            const float* xr = &x_lds[((row + di) * 8 + cg) * XSTR + colb];
            float4 A  = *(const float4*)&xr[0];
            float4 Bv = *(const float4*)&xr[4];
            float4 Cv = *(const float4*)&xr[8];
            float win[12] = {A.x, A.y, A.z, A.w, Bv.x, Bv.y, Bv.z, Bv.w,
                             Cv.x, Cv.y, Cv.z, Cv.w};
#pragma unroll
            for (int dj = 0; dj < 7; dj++)
#pragma unroll
                for (int kk = 0; kk < 4; kk++)
                    acc[kk] += win[kk + dj + 1] * wv[dj][kk];
        }
        float* op = &out[((size_t)b * CIN + g * 16 + half * 8 + cg) * HW + h * HDIM + colb];
        *(float4*)op = make_float4(acc[0], acc[1], acc[2], acc[3]);
    }
}

extern "C" void kernel_launch(void* const* d_in, const int* in_sizes, int n_in,
                              void* d_out, int out_size, void* d_ws, size_t ws_size,
                              hipStream_t stream) {
    const float* x     = (const float*)d_in[0];
    const float* W1    = (const float*)d_in[1];
    const float* b1    = (const float*)d_in[2];
    const float* gamma = (const float*)d_in[3];
    const float* beta  = (const float*)d_in[4];
    const float* mean  = (const float*)d_in[5];
    const float* var   = (const float*)d_in[6];
    const float* W2    = (const float*)d_in[7];
    const float* b2    = (const float*)d_in[8];
    float* out = (float*)d_out;

    unsigned short* t_bf = (unsigned short*)d_ws;          // 802816 ushorts
    unsigned short* W1b  = t_bf + (size_t)4 * HW * CR;     // 16384
    unsigned short* W2bT = W1b + CR * CIN;                 // 65536
    float* b1f           = (float*)(W2bT + NG * 64 * 64);  // 64

    int n_k0 = CR * CIN + NG * 64 * 64 + CR;
    k0_prep<<<(n_k0 + 255) / 256, 256, 0, stream>>>(
        W1, b1, gamma, beta, mean, var, W2, W1b, W2bT, b1f);

    dim3 g1(HW / 64, 4);
    k1_gemm<<<g1, 256, 0, stream>>>(x, W1b, b1f, t_bf);

    dim3 g2(NBAND, NG, 8);
    k2_fused<<<g2, 256, 0, stream>>>(x, t_bf, W2bT, b2, out);
}